// Round 3
// 3415.380 us; speedup vs baseline: 1.5488x; 1.5488x over previous
//
#include <hip/hip_runtime.h>
#include <hip/hip_bf16.h>

typedef __attribute__((ext_vector_type(8))) short bf16x8;
typedef __attribute__((ext_vector_type(4))) float f32x4;

#define T_STEPS 256
#define BATCH   64
#define KDIM    1024
#define HDIM    1024
#define NGATE   3072   // 3*HDIM
#define LAYERS  3
#define SLOTE   (BATCH * HDIM)       // elements per h slot
#define RING_SLOTS (T_STEPS + 1)
#define WSZ     (192L * 32 * 64 * 8) // swizzled weight elems per layer

#define MFMA16(a, b, c) __builtin_amdgcn_mfma_f32_16x16x32_bf16(a, b, c, 0, 0, 0)

// ---------- helpers (byte-identical to R6) ----------
__device__ __forceinline__ unsigned short f2b(float f) {
  union { float f; unsigned int u; } a; a.f = f;
  unsigned int u = a.u;
  unsigned int r = (u + 0x7FFFu + ((u >> 16) & 1u)) >> 16;  // RNE
  return (unsigned short)r;
}
__device__ __forceinline__ void gload16(const void* gptr, void* ldsptr) {
  __builtin_amdgcn_global_load_lds(
      (const __attribute__((address_space(1))) unsigned int*)gptr,
      (__attribute__((address_space(3))) unsigned int*)ldsptr,
      16, 0, 0);
}

// ---------- fp32 -> bf16 bulk convert (4 elems/thread) ----------
__global__ void f2b_kernel(const float* __restrict__ src,
                           unsigned short* __restrict__ dst, int n4) {
  int i = blockIdx.x * blockDim.x + threadIdx.x;
  if (i < n4) {
    float4 v = ((const float4*)src)[i];
    ushort4 o;
    o.x = f2b(v.x); o.y = f2b(v.y); o.z = f2b(v.z); o.w = f2b(v.w);
    ((ushort4*)dst)[i] = o;
  }
}

// ---------- swizzle a [3][3072][1024] fp32 matrix into MFMA frag layout ----------
// out: [l][ntile(192)][kc(32)][lane(64)][8 bf16]  (identical to R6)
// Per-lane addressing (idx16 = lane&15 -> n, k = kc*32+(lane>>4)*8) is identical
// for A- and B-fragments of mfma_16x16x32, so the same buffer serves the new
// A-operand (weights) role without change.
__global__ void swizzle_w(const float* __restrict__ w,
                          unsigned short* __restrict__ out) {
  long gid = (long)blockIdx.x * 256 + threadIdx.x;   // < 3*192*32*64
  int lane = (int)(gid & 63);
  long rest = gid >> 6;
  int kc = (int)(rest & 31); rest >>= 5;
  int ntile = (int)(rest % 192); int l = (int)(rest / 192);
  int n  = ntile * 16 + (lane & 15);
  int k0 = kc * 32 + (lane >> 4) * 8;
  const float* src = w + (((long)l * NGATE + n) * KDIM + k0);
  unsigned short o[8];
#pragma unroll
  for (int j = 0; j < 8; j++) o[j] = f2b(src[j]);
  bf16x8 v = *(bf16x8*)o;
  *(bf16x8*)(out + gid * 8) = v;
}

// ---------- fused 3-layer GRU, PLAIN launch, 192 wgs x 256 thr ----------
// R7 design (R6 sync idiom kept byte-identical):
//  (1) MFMA operand swap: D = W(A-frag) * h^T(B-frag). Each lane owns ONE
//      batch row (row = wave*16 + (lane&15)) and 4 CONSECUTIVE output cols
//      (cb..cb+3, cb = g*16 + (lane>>4)*4). Ring slots use a blocked layout
//      [g(64)][row(64)][16 cols] so the per-step h store is ONE coalesced 8B
//      agent store per lane (2KB contiguous per wg) instead of 1024 scattered
//      2B stores -> cheap vmcnt drain, full-line HBM writes. Consumer frag
//      loads stay 16B/lane: elem(row,k) = (k>>4)*1024 + row*16 + (k&15).
//  (2) x-GEMV software pipelining: x-GEMV(t+1) runs AFTER flag(t+2) publish
//      but BEFORE the own-layer flag poll, so its 96 MFMAs + Wih L2 streaming
//      hide inside the wait for the slowest peer wg. Prev-layer poll (>= t+3)
//      precedes the prev-ring read (slot write-once => no overwrite race).
__global__ __launch_bounds__(256, 1) void gru_fused(
    const unsigned short* __restrict__ xb,     // [T][64][1024] bf16 layer-0 input
    const unsigned short* __restrict__ wswhh,  // [3][WSZ] swizzled Whh
    const unsigned short* __restrict__ wswih,  // [3][WSZ] swizzled Wih
    const float* __restrict__ bih,             // [3][3072]
    const float* __restrict__ bhh,             // [3][3072]
    const float* __restrict__ h0,              // [3][64][1024]
    unsigned short* __restrict__ rings,        // [3][257][64*1024] bf16 (blocked slots)
    float* __restrict__ hout,                  // [3][64][1024] = d_out
    unsigned int* __restrict__ flags)          // [3][64], memset 0
{
  __shared__ alignas(16) unsigned short Bs[64 * 64 * 8];   // Whh r,z frags (64 KB)
  int l = blockIdx.x >> 6, g = blockIdx.x & 63;
  int tid = threadIdx.x, wave = tid >> 6, lane = tid & 63;
  int lg = lane >> 4;                      // lane group 0..3
  int row = wave * 16 + (lane & 15);       // batch row owned by this lane
  int cb  = g * 16 + lg * 4;               // first of 4 consecutive output cols

  const unsigned short* whh_l = wswhh + (size_t)l * WSZ;
  const unsigned short* wih_l = wswih + (size_t)l * WSZ;
  unsigned short* ring_l = rings + (size_t)l * RING_SLOTS * SLOTE;
  const unsigned short* prev_ring = rings + (size_t)(l - 1) * RING_SLOTS * SLOTE;
  unsigned int* fl = flags + l * 64;
  const unsigned int* fp = flags + (l > 0 ? (l - 1) : 0) * 64;

  // ---- stage Whh r,z into LDS (R6-identical) ----
#pragma unroll
  for (int i = 0; i < 16; i++) {
    int p = wave * 16 + i;                     // 0..63 = gate*32+kc
    int gate = p >> 5, kc = p & 31;
    gload16(whh_l + ((((long)gate * 64 + g) * 32 + kc) * 64 + lane) * 8,
            &Bs[(size_t)p * 512 + (size_t)lane * 8]);
  }
  // ---- Whh gate n into registers (R6-identical) ----
  bf16x8 bn[32];
#pragma unroll
  for (int kc = 0; kc < 32; kc++)
    bn[kc] = *(const bf16x8*)(whh_l + ((((long)(2 * 64 + g)) * 32 + kc) * 64 + lane) * 8);

  // ---- biases: 4 consecutive cols per lane -> float4 ----
  const float* bh_l = bhh + l * NGATE;
  const float* bi_l = bih + l * NGATE;
  float4 bhr4 = *(const float4*)(bh_l + 0 * HDIM + cb);
  float4 bhz4 = *(const float4*)(bh_l + 1 * HDIM + cb);
  float4 bhn4 = *(const float4*)(bh_l + 2 * HDIM + cb);
  float4 bir4 = *(const float4*)(bi_l + 0 * HDIM + cb);
  float4 biz4 = *(const float4*)(bi_l + 1 * HDIM + cb);
  float4 bin4 = *(const float4*)(bi_l + 2 * HDIM + cb);
  float br_[4]  = {bir4.x + bhr4.x, bir4.y + bhr4.y, bir4.z + bhr4.z, bir4.w + bhr4.w};
  float bz_[4]  = {biz4.x + bhz4.x, biz4.y + bhz4.y, biz4.z + bhz4.z, biz4.w + bhz4.w};
  float bi_n[4] = {bin4.x, bin4.y, bin4.z, bin4.w};
  float bh_n[4] = {bhn4.x, bhn4.y, bhn4.z, bhn4.w};

  // ---- x-GEMV (computes gi(tt) into air/aiz/ain); W is the A operand ----
  f32x4 air, aiz, ain;
  auto xgemv = [&](int tt) {
    f32x4 z = {};
    air = z; aiz = z; ain = z;
    if (l == 0) {
      // xb is linear [t][row][1024]
      const unsigned short* xa_b = xb + (size_t)tt * SLOTE + (size_t)row * KDIM + lg * 8;
#pragma unroll
      for (int kb = 0; kb < 4; kb++) {
        bf16x8 xa[8];
#pragma unroll
        for (int j = 0; j < 8; j++)
          xa[j] = *(const bf16x8*)(xa_b + (size_t)(kb * 8 + j) * 32);
#pragma unroll
        for (int j = 0; j < 8; j++) {
          int kc = kb * 8 + j;
          bf16x8 wir = *(const bf16x8*)(wih_l + ((((long)(0 * 64 + g)) * 32 + kc) * 64 + lane) * 8);
          bf16x8 wiz = *(const bf16x8*)(wih_l + ((((long)(1 * 64 + g)) * 32 + kc) * 64 + lane) * 8);
          bf16x8 win = *(const bf16x8*)(wih_l + ((((long)(2 * 64 + g)) * 32 + kc) * 64 + lane) * 8);
          air = MFMA16(wir, xa[j], air);
          aiz = MFMA16(wiz, xa[j], aiz);
          ain = MFMA16(win, xa[j], ain);
        }
      }
    } else {
      // prev ring slot (T-1-tt) in blocked layout: elem = (k>>4)*1024 + row*16 + (k&15)
      const unsigned short* xa_b = prev_ring + (size_t)(T_STEPS - 1 - tt) * SLOTE
                                   + (size_t)(lg >> 1) * 1024 + (size_t)row * 16 + (lg & 1) * 8;
#pragma unroll
      for (int kb = 0; kb < 4; kb++) {
        bf16x8 xa[8];
#pragma unroll
        for (int j = 0; j < 8; j++)
          xa[j] = *(const bf16x8*)(xa_b + (size_t)(kb * 8 + j) * 2048);
#pragma unroll
        for (int j = 0; j < 8; j++) {
          int kc = kb * 8 + j;
          bf16x8 wir = *(const bf16x8*)(wih_l + ((((long)(0 * 64 + g)) * 32 + kc) * 64 + lane) * 8);
          bf16x8 wiz = *(const bf16x8*)(wih_l + ((((long)(1 * 64 + g)) * 32 + kc) * 64 + lane) * 8);
          bf16x8 win = *(const bf16x8*)(wih_l + ((((long)(2 * 64 + g)) * 32 + kc) * 64 + lane) * 8);
          air = MFMA16(wir, xa[j], air);
          aiz = MFMA16(wiz, xa[j], aiz);
          ain = MFMA16(win, xa[j], ain);
        }
      }
    }
  };

  // ---- publish h(0)=h0 into own ring slot T (blocked, one 8B store) ----
  float h[4];
  {
    float4 h4 = *(const float4*)(h0 + (size_t)l * SLOTE + (size_t)row * HDIM + cb);
    h[0] = h4.x; h[1] = h4.y; h[2] = h4.z; h[3] = h4.w;
    union { unsigned short us[4]; unsigned long long u; } pk;
#pragma unroll
    for (int r = 0; r < 4; r++) pk.us[r] = f2b(h[r]);
    unsigned short* slotT = ring_l + (size_t)T_STEPS * SLOTE;
    __hip_atomic_store((unsigned long long*)(slotT + (size_t)g * 1024 + (size_t)row * 16 + lg * 4),
                       pk.u, __ATOMIC_RELAXED, __HIP_MEMORY_SCOPE_AGENT);
  }
  __syncthreads();   // drains vmcnt: Bs staged + h0 at LLC
  if (tid == 0)
    __hip_atomic_store(&fl[g], 1u, __ATOMIC_RELAXED, __HIP_MEMORY_SCOPE_AGENT);

  // pre-loop wait: own h0 published everywhere; prev layer finished step 0
  while (__hip_atomic_load(&fl[lane], __ATOMIC_RELAXED,
                           __HIP_MEMORY_SCOPE_AGENT) < 1u) {}
  if (l > 0) {
    while (__hip_atomic_load(&fp[lane], __ATOMIC_RELAXED,
                             __HIP_MEMORY_SCOPE_AGENT) < 2u) {}
  }
  __syncthreads();

  xgemv(0);   // x projection for step 0 (inputs already guarded above)

#pragma unroll 1
  for (int t = 0; t < T_STEPS; t++) {
    // ---- h(t) B-frags from own slot (T-t), blocked layout ----
    const unsigned short* ha_b = ring_l + (size_t)(T_STEPS - t) * SLOTE
                                 + (size_t)(lg >> 1) * 1024 + (size_t)row * 16 + (lg & 1) * 8;
    bf16x8 ha[32];
#pragma unroll
    for (int kc = 0; kc < 32; kc++)
      ha[kc] = *(const bf16x8*)(ha_b + (size_t)kc * 2048);

    // ---- h GEMV: Whh r,z from LDS, n from regs; W is A operand ----
    f32x4 ahr = {}, ahz = {}, ahn = {};
#pragma unroll
    for (int kc = 0; kc < 32; kc++) {
      bf16x8 whr = *(const bf16x8*)&Bs[(size_t)(0 * 32 + kc) * 512 + (size_t)lane * 8];
      bf16x8 whz = *(const bf16x8*)&Bs[(size_t)(1 * 32 + kc) * 512 + (size_t)lane * 8];
      ahr = MFMA16(whr, ha[kc], ahr);
      ahz = MFMA16(whz, ha[kc], ahz);
      ahn = MFMA16(bn[kc], ha[kc], ahn);
    }

    // ---- gates + state update (D: col=lane&15 -> batch row, row=lg*4+r -> out col) ----
    unsigned short* hn = ring_l + (size_t)(T_STEPS - 1 - t) * SLOTE;  // h(t+1)
    union { unsigned short us[4]; unsigned long long u; } pk;
#pragma unroll
    for (int r = 0; r < 4; r++) {
      float xr = air[r] + ahr[r] + br_[r];
      float xz = aiz[r] + ahz[r] + bz_[r];
      float rr = 1.0f / (1.0f + __expf(-xr));
      float zz = 1.0f / (1.0f + __expf(-xz));
      float xn = (ain[r] + bi_n[r]) + rr * (ahn[r] + bh_n[r]);
      float e2 = __expf(-2.0f * xn);
      float nn = (1.0f - e2) / (1.0f + e2);    // tanh
      float hv = (1.0f - zz) * nn + zz * h[r];
      h[r] = hv;
      pk.us[r] = f2b(hv);
    }
    __hip_atomic_store((unsigned long long*)(hn + (size_t)g * 1024 + (size_t)row * 16 + lg * 4),
                       pk.u, __ATOMIC_RELAXED, __HIP_MEMORY_SCOPE_AGENT);
    if (t == T_STEPS - 1) {
      float4 o; o.x = h[0]; o.y = h[1]; o.z = h[2]; o.w = h[3];
      *(float4*)(hout + (size_t)l * SLOTE + (size_t)row * HDIM + cb) = o;
    }

    // ---- barrier (R6 idiom) with x-GEMV(t+1) hidden inside the own-flag wait ----
    __syncthreads();                           // all waves' h(t+1) stores at LLC
    if (tid == 0)
      __hip_atomic_store(&fl[g], (unsigned)(t + 2),
                         __ATOMIC_RELAXED, __HIP_MEMORY_SCOPE_AGENT);
    if (t + 1 < T_STEPS) {
      if (l > 0) {   // prev slot (T-2-t) must be ready BEFORE xgemv reads it
        while (__hip_atomic_load(&fp[lane], __ATOMIC_RELAXED,
                                 __HIP_MEMORY_SCOPE_AGENT) < (unsigned)(t + 3)) {}
      }
      xgemv(t + 1);  // overlaps with peers finishing step t
      while (__hip_atomic_load(&fl[lane], __ATOMIC_RELAXED,
                               __HIP_MEMORY_SCOPE_AGENT) < (unsigned)(t + 2)) {}
    }
    __syncthreads();
  }
}

// ---------- host ----------
extern "C" void kernel_launch(void* const* d_in, const int* in_sizes, int n_in,
                              void* d_out, int out_size, void* d_ws, size_t ws_size,
                              hipStream_t stream) {
  const float* x   = (const float*)d_in[0];
  const float* h0  = (const float*)d_in[1];
  const float* wih = (const float*)d_in[2];
  const float* whh = (const float*)d_in[3];
  const float* bih = (const float*)d_in[4];
  const float* bhh = (const float*)d_in[5];
  float* out = (float*)d_out;

  char* p = (char*)d_ws;
  unsigned short* xb    = (unsigned short*)p; p += (size_t)T_STEPS * SLOTE * 2;             // 33.6 MB
  unsigned short* wswhh = (unsigned short*)p; p += (size_t)LAYERS * WSZ * 2;                // 18.9 MB
  unsigned short* wswih = (unsigned short*)p; p += (size_t)LAYERS * WSZ * 2;                // 18.9 MB
  unsigned short* rings = (unsigned short*)p; p += (size_t)LAYERS * RING_SLOTS * SLOTE * 2; // 101 MB
  unsigned int*   flags = (unsigned int*)p;   p += 4096;
  // total ~172.5 MB

  hipMemsetAsync(flags, 0, 4096, stream);
  f2b_kernel<<<16384, 256, 0, stream>>>(x, xb, (T_STEPS * SLOTE) / 4);
  swizzle_w<<<4608, 256, 0, stream>>>(whh, wswhh);
  swizzle_w<<<4608, 256, 0, stream>>>(wih, wswih);

  gru_fused<<<LAYERS * 64, 256, 0, stream>>>(
      xb, wswhh, wswih, bih, bhh, h0, rings, out, flags);
}

// Round 4
// 3327.262 us; speedup vs baseline: 1.5898x; 1.0265x over previous
//
#include <hip/hip_runtime.h>
#include <hip/hip_bf16.h>

typedef __attribute__((ext_vector_type(8))) short bf16x8;
typedef __attribute__((ext_vector_type(4))) float f32x4;

#define T_STEPS 256
#define BATCH   64
#define KDIM    1024
#define HDIM    1024
#define NGATE   3072   // 3*HDIM
#define LAYERS  3
#define SLOTE   (BATCH * HDIM)       // elements per h slot
#define RING_SLOTS (T_STEPS + 1)
#define WSZ     (192L * 32 * 64 * 8) // swizzled weight elems per layer
#define FSTRIDE 4                    // uints per flag (16 B padding: 4 writers/line)

#define MFMA16(a, b, c) __builtin_amdgcn_mfma_f32_16x16x32_bf16(a, b, c, 0, 0, 0)

// ---------- helpers (byte-identical to R6) ----------
__device__ __forceinline__ unsigned short f2b(float f) {
  union { float f; unsigned int u; } a; a.f = f;
  unsigned int u = a.u;
  unsigned int r = (u + 0x7FFFu + ((u >> 16) & 1u)) >> 16;  // RNE
  return (unsigned short)r;
}
__device__ __forceinline__ void gload16(const void* gptr, void* ldsptr) {
  __builtin_amdgcn_global_load_lds(
      (const __attribute__((address_space(1))) unsigned int*)gptr,
      (__attribute__((address_space(3))) unsigned int*)ldsptr,
      16, 0, 0);
}

// ---------- fp32 -> bf16 bulk convert (4 elems/thread) ----------
__global__ void f2b_kernel(const float* __restrict__ src,
                           unsigned short* __restrict__ dst, int n4) {
  int i = blockIdx.x * blockDim.x + threadIdx.x;
  if (i < n4) {
    float4 v = ((const float4*)src)[i];
    ushort4 o;
    o.x = f2b(v.x); o.y = f2b(v.y); o.z = f2b(v.z); o.w = f2b(v.w);
    ((ushort4*)dst)[i] = o;
  }
}

// ---------- swizzle a [3][3072][1024] fp32 matrix into MFMA frag layout ----------
// out: [l][ntile(192)][kc(32)][lane(64)][8 bf16]  (identical to R6/R7)
__global__ void swizzle_w(const float* __restrict__ w,
                          unsigned short* __restrict__ out) {
  long gid = (long)blockIdx.x * 256 + threadIdx.x;   // < 3*192*32*64
  int lane = (int)(gid & 63);
  long rest = gid >> 6;
  int kc = (int)(rest & 31); rest >>= 5;
  int ntile = (int)(rest % 192); int l = (int)(rest / 192);
  int n  = ntile * 16 + (lane & 15);
  int k0 = kc * 32 + (lane >> 4) * 8;
  const float* src = w + (((long)l * NGATE + n) * KDIM + k0);
  unsigned short o[8];
#pragma unroll
  for (int j = 0; j < 8; j++) o[j] = f2b(src[j]);
  bf16x8 v = *(bf16x8*)o;
  *(bf16x8*)(out + gid * 8) = v;
}

// ---------- fused 3-layer GRU, PLAIN launch, 192 wgs x 256 thr ----------
// R8 changes vs R7 (flag values/ordering semantics IDENTICAL):
//  (1) Flags padded to 16 B stride: 64 producer stores per layer per step now
//      spread over 16 cache lines (4 writers/line) instead of 4 (16/line) ->
//      less exclusive-line bouncing on the critical flag-publish path.
//  (2) Wave-0-only polling + release __syncthreads: 4x less agent-scope poll
//      traffic contending with flag stores; ring loads now always sit behind
//      a barrier after the poll (compiler-safe vs hoisting past relaxed
//      atomics, which R7 merely got away with).
// Carried from R7: operand-swapped MFMA (W=A, h^T=B), blocked ring slots
// [g][row][16] with one coalesced 8B agent store/lane, x-GEMV(t+1) pipelined
// between flag publish and own-layer poll.
__global__ __launch_bounds__(256, 1) void gru_fused(
    const unsigned short* __restrict__ xb,     // [T][64][1024] bf16 layer-0 input
    const unsigned short* __restrict__ wswhh,  // [3][WSZ] swizzled Whh
    const unsigned short* __restrict__ wswih,  // [3][WSZ] swizzled Wih
    const float* __restrict__ bih,             // [3][3072]
    const float* __restrict__ bhh,             // [3][3072]
    const float* __restrict__ h0,              // [3][64][1024]
    unsigned short* __restrict__ rings,        // [3][257][64*1024] bf16 (blocked slots)
    float* __restrict__ hout,                  // [3][64][1024] = d_out
    unsigned int* __restrict__ flags)          // [3][64][FSTRIDE], memset 0
{
  __shared__ alignas(16) unsigned short Bs[64 * 64 * 8];   // Whh r,z frags (64 KB)
  int l = blockIdx.x >> 6, g = blockIdx.x & 63;
  int tid = threadIdx.x, wave = tid >> 6, lane = tid & 63;
  int lg = lane >> 4;                      // lane group 0..3
  int row = wave * 16 + (lane & 15);       // batch row owned by this lane
  int cb  = g * 16 + lg * 4;               // first of 4 consecutive output cols

  const unsigned short* whh_l = wswhh + (size_t)l * WSZ;
  const unsigned short* wih_l = wswih + (size_t)l * WSZ;
  unsigned short* ring_l = rings + (size_t)l * RING_SLOTS * SLOTE;
  const unsigned short* prev_ring = rings + (size_t)(l - 1) * RING_SLOTS * SLOTE;
  unsigned int* fl = flags + (size_t)l * 64 * FSTRIDE;
  const unsigned int* fp = flags + (size_t)(l > 0 ? (l - 1) : 0) * 64 * FSTRIDE;

  // ---- stage Whh r,z into LDS (R6-identical) ----
#pragma unroll
  for (int i = 0; i < 16; i++) {
    int p = wave * 16 + i;                     // 0..63 = gate*32+kc
    int gate = p >> 5, kc = p & 31;
    gload16(whh_l + ((((long)gate * 64 + g) * 32 + kc) * 64 + lane) * 8,
            &Bs[(size_t)p * 512 + (size_t)lane * 8]);
  }
  // ---- Whh gate n into registers (R6-identical) ----
  bf16x8 bn[32];
#pragma unroll
  for (int kc = 0; kc < 32; kc++)
    bn[kc] = *(const bf16x8*)(whh_l + ((((long)(2 * 64 + g)) * 32 + kc) * 64 + lane) * 8);

  // ---- biases: 4 consecutive cols per lane -> float4 ----
  const float* bh_l = bhh + l * NGATE;
  const float* bi_l = bih + l * NGATE;
  float4 bhr4 = *(const float4*)(bh_l + 0 * HDIM + cb);
  float4 bhz4 = *(const float4*)(bh_l + 1 * HDIM + cb);
  float4 bhn4 = *(const float4*)(bh_l + 2 * HDIM + cb);
  float4 bir4 = *(const float4*)(bi_l + 0 * HDIM + cb);
  float4 biz4 = *(const float4*)(bi_l + 1 * HDIM + cb);
  float4 bin4 = *(const float4*)(bi_l + 2 * HDIM + cb);
  float br_[4]  = {bir4.x + bhr4.x, bir4.y + bhr4.y, bir4.z + bhr4.z, bir4.w + bhr4.w};
  float bz_[4]  = {biz4.x + bhz4.x, biz4.y + bhz4.y, biz4.z + bhz4.z, biz4.w + bhz4.w};
  float bi_n[4] = {bin4.x, bin4.y, bin4.z, bin4.w};
  float bh_n[4] = {bhn4.x, bhn4.y, bhn4.z, bhn4.w};

  // ---- x-GEMV (computes gi(tt) into air/aiz/ain); W is the A operand ----
  f32x4 air, aiz, ain;
  auto xgemv = [&](int tt) {
    f32x4 z = {};
    air = z; aiz = z; ain = z;
    if (l == 0) {
      // xb is linear [t][row][1024]
      const unsigned short* xa_b = xb + (size_t)tt * SLOTE + (size_t)row * KDIM + lg * 8;
#pragma unroll
      for (int kb = 0; kb < 4; kb++) {
        bf16x8 xa[8];
#pragma unroll
        for (int j = 0; j < 8; j++)
          xa[j] = *(const bf16x8*)(xa_b + (size_t)(kb * 8 + j) * 32);
#pragma unroll
        for (int j = 0; j < 8; j++) {
          int kc = kb * 8 + j;
          bf16x8 wir = *(const bf16x8*)(wih_l + ((((long)(0 * 64 + g)) * 32 + kc) * 64 + lane) * 8);
          bf16x8 wiz = *(const bf16x8*)(wih_l + ((((long)(1 * 64 + g)) * 32 + kc) * 64 + lane) * 8);
          bf16x8 win = *(const bf16x8*)(wih_l + ((((long)(2 * 64 + g)) * 32 + kc) * 64 + lane) * 8);
          air = MFMA16(wir, xa[j], air);
          aiz = MFMA16(wiz, xa[j], aiz);
          ain = MFMA16(win, xa[j], ain);
        }
      }
    } else {
      // prev ring slot (T-1-tt) in blocked layout: elem = (k>>4)*1024 + row*16 + (k&15)
      const unsigned short* xa_b = prev_ring + (size_t)(T_STEPS - 1 - tt) * SLOTE
                                   + (size_t)(lg >> 1) * 1024 + (size_t)row * 16 + (lg & 1) * 8;
#pragma unroll
      for (int kb = 0; kb < 4; kb++) {
        bf16x8 xa[8];
#pragma unroll
        for (int j = 0; j < 8; j++)
          xa[j] = *(const bf16x8*)(xa_b + (size_t)(kb * 8 + j) * 2048);
#pragma unroll
        for (int j = 0; j < 8; j++) {
          int kc = kb * 8 + j;
          bf16x8 wir = *(const bf16x8*)(wih_l + ((((long)(0 * 64 + g)) * 32 + kc) * 64 + lane) * 8);
          bf16x8 wiz = *(const bf16x8*)(wih_l + ((((long)(1 * 64 + g)) * 32 + kc) * 64 + lane) * 8);
          bf16x8 win = *(const bf16x8*)(wih_l + ((((long)(2 * 64 + g)) * 32 + kc) * 64 + lane) * 8);
          air = MFMA16(wir, xa[j], air);
          aiz = MFMA16(wiz, xa[j], aiz);
          ain = MFMA16(win, xa[j], ain);
        }
      }
    }
  };

  // ---- publish h(0)=h0 into own ring slot T (blocked, one 8B store) ----
  float h[4];
  {
    float4 h4 = *(const float4*)(h0 + (size_t)l * SLOTE + (size_t)row * HDIM + cb);
    h[0] = h4.x; h[1] = h4.y; h[2] = h4.z; h[3] = h4.w;
    union { unsigned short us[4]; unsigned long long u; } pk;
#pragma unroll
    for (int r = 0; r < 4; r++) pk.us[r] = f2b(h[r]);
    unsigned short* slotT = ring_l + (size_t)T_STEPS * SLOTE;
    __hip_atomic_store((unsigned long long*)(slotT + (size_t)g * 1024 + (size_t)row * 16 + lg * 4),
                       pk.u, __ATOMIC_RELAXED, __HIP_MEMORY_SCOPE_AGENT);
  }
  __syncthreads();   // drains vmcnt: Bs staged + h0 at LLC
  if (tid == 0)
    __hip_atomic_store(&fl[g * FSTRIDE], 1u, __ATOMIC_RELAXED, __HIP_MEMORY_SCOPE_AGENT);

  // pre-loop wait (wave 0 only): own h0 published everywhere; prev layer step 0 done
  if (wave == 0) {
    while (__hip_atomic_load(&fl[lane * FSTRIDE], __ATOMIC_RELAXED,
                             __HIP_MEMORY_SCOPE_AGENT) < 1u) {}
    if (l > 0) {
      while (__hip_atomic_load(&fp[lane * FSTRIDE], __ATOMIC_RELAXED,
                               __HIP_MEMORY_SCOPE_AGENT) < 2u) {}
    }
  }
  __syncthreads();   // release: data behind those flags visible to all waves

  xgemv(0);   // x projection for step 0 (inputs guarded above)

#pragma unroll 1
  for (int t = 0; t < T_STEPS; t++) {
    // ---- h(t) B-frags from own slot (T-t), blocked layout ----
    const unsigned short* ha_b = ring_l + (size_t)(T_STEPS - t) * SLOTE
                                 + (size_t)(lg >> 1) * 1024 + (size_t)row * 16 + (lg & 1) * 8;
    bf16x8 ha[32];
#pragma unroll
    for (int kc = 0; kc < 32; kc++)
      ha[kc] = *(const bf16x8*)(ha_b + (size_t)kc * 2048);

    // ---- h GEMV: Whh r,z from LDS, n from regs; W is A operand ----
    f32x4 ahr = {}, ahz = {}, ahn = {};
#pragma unroll
    for (int kc = 0; kc < 32; kc++) {
      bf16x8 whr = *(const bf16x8*)&Bs[(size_t)(0 * 32 + kc) * 512 + (size_t)lane * 8];
      bf16x8 whz = *(const bf16x8*)&Bs[(size_t)(1 * 32 + kc) * 512 + (size_t)lane * 8];
      ahr = MFMA16(whr, ha[kc], ahr);
      ahz = MFMA16(whz, ha[kc], ahz);
      ahn = MFMA16(bn[kc], ha[kc], ahn);
    }

    // ---- gates + state update (D: col=lane&15 -> batch row, row=lg*4+r -> out col) ----
    unsigned short* hn = ring_l + (size_t)(T_STEPS - 1 - t) * SLOTE;  // h(t+1)
    union { unsigned short us[4]; unsigned long long u; } pk;
#pragma unroll
    for (int r = 0; r < 4; r++) {
      float xr = air[r] + ahr[r] + br_[r];
      float xz = aiz[r] + ahz[r] + bz_[r];
      float rr = 1.0f / (1.0f + __expf(-xr));
      float zz = 1.0f / (1.0f + __expf(-xz));
      float xn = (ain[r] + bi_n[r]) + rr * (ahn[r] + bh_n[r]);
      float e2 = __expf(-2.0f * xn);
      float nn = (1.0f - e2) / (1.0f + e2);    // tanh
      float hv = (1.0f - zz) * nn + zz * h[r];
      h[r] = hv;
      pk.us[r] = f2b(hv);
    }
    __hip_atomic_store((unsigned long long*)(hn + (size_t)g * 1024 + (size_t)row * 16 + lg * 4),
                       pk.u, __ATOMIC_RELAXED, __HIP_MEMORY_SCOPE_AGENT);
    if (t == T_STEPS - 1) {
      float4 o; o.x = h[0]; o.y = h[1]; o.z = h[2]; o.w = h[3];
      *(float4*)(hout + (size_t)l * SLOTE + (size_t)row * HDIM + cb) = o;
    }

    // ---- barrier: drain, publish, wave0-only polls with release barriers ----
    __syncthreads();                           // all waves' h(t+1) stores at LLC
    if (tid == 0)
      __hip_atomic_store(&fl[g * FSTRIDE], (unsigned)(t + 2),
                         __ATOMIC_RELAXED, __HIP_MEMORY_SCOPE_AGENT);
    if (t + 1 < T_STEPS) {
      if (l > 0 && wave == 0) {  // prev slot (T-2-t) ready before xgemv reads it
        while (__hip_atomic_load(&fp[lane * FSTRIDE], __ATOMIC_RELAXED,
                                 __HIP_MEMORY_SCOPE_AGENT) < (unsigned)(t + 3)) {}
      }
      __syncthreads();           // release: prev-layer data visible to all waves
      xgemv(t + 1);              // overlaps with peers finishing step t
      if (wave == 0) {
        while (__hip_atomic_load(&fl[lane * FSTRIDE], __ATOMIC_RELAXED,
                                 __HIP_MEMORY_SCOPE_AGENT) < (unsigned)(t + 2)) {}
      }
      __syncthreads();           // release: peers' h(t+1) visible to all waves
    }
  }
}

// ---------- host ----------
extern "C" void kernel_launch(void* const* d_in, const int* in_sizes, int n_in,
                              void* d_out, int out_size, void* d_ws, size_t ws_size,
                              hipStream_t stream) {
  const float* x   = (const float*)d_in[0];
  const float* h0  = (const float*)d_in[1];
  const float* wih = (const float*)d_in[2];
  const float* whh = (const float*)d_in[3];
  const float* bih = (const float*)d_in[4];
  const float* bhh = (const float*)d_in[5];
  float* out = (float*)d_out;

  char* p = (char*)d_ws;
  unsigned short* xb    = (unsigned short*)p; p += (size_t)T_STEPS * SLOTE * 2;             // 33.6 MB
  unsigned short* wswhh = (unsigned short*)p; p += (size_t)LAYERS * WSZ * 2;                // 18.9 MB
  unsigned short* wswih = (unsigned short*)p; p += (size_t)LAYERS * WSZ * 2;                // 18.9 MB
  unsigned short* rings = (unsigned short*)p; p += (size_t)LAYERS * RING_SLOTS * SLOTE * 2; // 101 MB
  unsigned int*   flags = (unsigned int*)p;   p += 4096;  // 3*64*FSTRIDE*4 = 3 KB used
  // total ~172.5 MB

  hipMemsetAsync(flags, 0, 4096, stream);
  f2b_kernel<<<16384, 256, 0, stream>>>(x, xb, (T_STEPS * SLOTE) / 4);
  swizzle_w<<<4608, 256, 0, stream>>>(whh, wswhh);
  swizzle_w<<<4608, 256, 0, stream>>>(wih, wswih);

  gru_fused<<<LAYERS * 64, 256, 0, stream>>>(
      xb, wswhh, wswih, bih, bhh, h0, rings, out, flags);
}

// Round 6
// 2339.536 us; speedup vs baseline: 2.2610x; 1.4222x over previous
//
#include <hip/hip_runtime.h>
#include <hip/hip_bf16.h>

typedef __attribute__((ext_vector_type(8))) short bf16x8;
typedef __attribute__((ext_vector_type(4))) float f32x4;

#define T_STEPS 256
#define BATCH   64
#define KDIM    1024
#define HDIM    1024
#define NGATE   3072   // 3*HDIM
#define LAYERS  3
#define SLOTE   (BATCH * HDIM)       // elements per h slot
#define RING_SLOTS (T_STEPS + 1)
#define WSZ     (192L * 32 * 64 * 8) // swizzled weight elems per layer
#define FSTRIDE 4                    // uints per flag (16 B padding)

#define LDS_BS_BYTES  65536                  // Whh r,z frags
#define LDS_WIS_BYTES 65536                  // Wih r,z frags
#define LDS_GI_BYTES  (2 * 3 * 64 * 16 * 4)  // gi double buffer (24 KB)
#define LDS_TOTAL (LDS_BS_BYTES + LDS_WIS_BYTES + LDS_GI_BYTES)  // 155648 <= 160 KB

#define MFMA16(a, b, c) __builtin_amdgcn_mfma_f32_16x16x32_bf16(a, b, c, 0, 0, 0)

// ---------- helpers (byte-identical to R6) ----------
__device__ __forceinline__ unsigned short f2b(float f) {
  union { float f; unsigned int u; } a; a.f = f;
  unsigned int u = a.u;
  unsigned int r = (u + 0x7FFFu + ((u >> 16) & 1u)) >> 16;  // RNE
  return (unsigned short)r;
}
__device__ __forceinline__ void gload16(const void* gptr, void* ldsptr) {
  __builtin_amdgcn_global_load_lds(
      (const __attribute__((address_space(1))) unsigned int*)gptr,
      (__attribute__((address_space(3))) unsigned int*)ldsptr,
      16, 0, 0);
}

// ---------- fp32 -> bf16 bulk convert (4 elems/thread) ----------
__global__ void f2b_kernel(const float* __restrict__ src,
                           unsigned short* __restrict__ dst, int n4) {
  int i = blockIdx.x * blockDim.x + threadIdx.x;
  if (i < n4) {
    float4 v = ((const float4*)src)[i];
    ushort4 o;
    o.x = f2b(v.x); o.y = f2b(v.y); o.z = f2b(v.z); o.w = f2b(v.w);
    ((ushort4*)dst)[i] = o;
  }
}

// ---------- swizzle a [3][3072][1024] fp32 matrix into MFMA frag layout ----------
// out: [l][ntile(192)][kc(32)][lane(64)][8 bf16]  (identical to R6/R7/R8)
__global__ void swizzle_w(const float* __restrict__ w,
                          unsigned short* __restrict__ out) {
  long gid = (long)blockIdx.x * 256 + threadIdx.x;   // < 3*192*32*64
  int lane = (int)(gid & 63);
  long rest = gid >> 6;
  int kc = (int)(rest & 31); rest >>= 5;
  int ntile = (int)(rest % 192); int l = (int)(rest / 192);
  int n  = ntile * 16 + (lane & 15);
  int k0 = kc * 32 + (lane >> 4) * 8;
  const float* src = w + (((long)l * NGATE + n) * KDIM + k0);
  unsigned short o[8];
#pragma unroll
  for (int j = 0; j < 8; j++) o[j] = f2b(src[j]);
  bf16x8 v = *(bf16x8*)o;
  *(bf16x8*)(out + gid * 8) = v;
}

// ---------- fused 3-layer GRU, 192 wgs x 512 thr, wave-role specialized ----------
// R9 design:
//  * 8 waves = 2 waves/SIMD (TLP for latency hiding; VGPR<=256 via launch_bounds).
//  * h-waves (0..3): recurrent chain only. rg=wave, rows rg*16+(lane&15), full K.
//    Whh r,z from LDS Bs; Whh n in regs (wn). Reads gi(t) from LDS double buffer.
//  * x-waves (4..7): compute gi(t+1)=Wih*x(t+1) concurrently. Wih r,z from LDS
//    Wis (de-duplicated: 1 LDS fill at start vs 4x L2 re-reads/step); Wih n in
//    regs (wn). Only x-waves poll prev-layer flags; write gi to LDS buf (t+1)&1.
//  * ONE __syncthreads per step, in uniform control flow. Safety: gi buffers
//    alternate parity (h reads t&1 before B1(t); x writes (t+1)&1 before B1(t);
//    x's next write to t&1 happens after B1(t+1), h's read of it was before B1(t)).
//  * Flag protocol identical to R8 (monotone, padded, publish-after-drain);
//    ring slots write-once; all h-wave polls precede their ha loads.
__global__ __launch_bounds__(512, 2) void gru_fused(
    const unsigned short* __restrict__ xb,     // [T][64][1024] bf16 layer-0 input
    const unsigned short* __restrict__ wswhh,  // [3][WSZ] swizzled Whh
    const unsigned short* __restrict__ wswih,  // [3][WSZ] swizzled Wih
    const float* __restrict__ bih,             // [3][3072]
    const float* __restrict__ bhh,             // [3][3072]
    const float* __restrict__ h0,              // [3][64][1024]
    unsigned short* __restrict__ rings,        // [3][257][64*1024] bf16 (blocked slots)
    float* __restrict__ hout,                  // [3][64][1024] = d_out
    unsigned int* __restrict__ flags)          // [3][64][FSTRIDE], memset 0
{
  extern __shared__ __align__(16) char smem[];
  unsigned short* Bs  = (unsigned short*)smem;                       // [64][512] ushort
  unsigned short* Wis = (unsigned short*)(smem + LDS_BS_BYTES);      // [64][512] ushort
  float* gi_lds = (float*)(smem + LDS_BS_BYTES + LDS_WIS_BYTES);     // [2][3][64][16] f32

  int l = blockIdx.x >> 6, g = blockIdx.x & 63;
  int tid = threadIdx.x, wave = tid >> 6, lane = tid & 63;
  int lg = lane >> 4;
  int rg = wave & 3;                        // row-group for both roles
  bool is_h = (wave < 4);
  int row = rg * 16 + (lane & 15);          // batch row owned by this lane
  int cb  = g * 16 + lg * 4;                // first of 4 consecutive output cols

  const unsigned short* whh_l = wswhh + (size_t)l * WSZ;
  const unsigned short* wih_l = wswih + (size_t)l * WSZ;
  unsigned short* ring_l = rings + (size_t)l * RING_SLOTS * SLOTE;
  const unsigned short* prev_ring = rings + (size_t)(l - 1) * RING_SLOTS * SLOTE;
  unsigned int* fl = flags + (size_t)l * 64 * FSTRIDE;
  const unsigned int* fp = flags + (size_t)(l > 0 ? (l - 1) : 0) * 64 * FSTRIDE;

  // ---- stage Whh r,z (rows 0..63) and Wih r,z (rows 64..127) into LDS ----
#pragma unroll
  for (int i = 0; i < 16; i++) {
    int p = wave * 16 + i;                  // 0..127
    int gate = (p >> 5) & 1;                // 0=r,1=z within its matrix
    int kc = p & 31;
    const unsigned short* src = (p < 64)
        ? whh_l + ((((long)gate * 64 + g) * 32 + kc) * 64 + lane) * 8
        : wih_l + ((((long)gate * 64 + g) * 32 + kc) * 64 + lane) * 8;
    unsigned short* dst = (p < 64)
        ? &Bs[(size_t)p * 512 + (size_t)lane * 8]
        : &Wis[(size_t)(p - 64) * 512 + (size_t)lane * 8];
    gload16(src, dst);
  }

  // ---- gate-n weights into registers: Whh-n for h-waves, Wih-n for x-waves ----
  bf16x8 wn[32];
  {
    const unsigned short* base = is_h ? whh_l : wih_l;
#pragma unroll
    for (int kc = 0; kc < 32; kc++)
      wn[kc] = *(const bf16x8*)(base + ((((long)(2 * 64 + g)) * 32 + kc) * 64 + lane) * 8);
  }

  // ---- biases (h-waves only) ----
  float br_[4], bz_[4], bi_n[4], bh_n[4];
  float h[4] = {0.f, 0.f, 0.f, 0.f};
  if (is_h) {
    const float* bh_l = bhh + l * NGATE;
    const float* bi_l = bih + l * NGATE;
    float4 bhr4 = *(const float4*)(bh_l + 0 * HDIM + cb);
    float4 bhz4 = *(const float4*)(bh_l + 1 * HDIM + cb);
    float4 bhn4 = *(const float4*)(bh_l + 2 * HDIM + cb);
    float4 bir4 = *(const float4*)(bi_l + 0 * HDIM + cb);
    float4 biz4 = *(const float4*)(bi_l + 1 * HDIM + cb);
    float4 bin4 = *(const float4*)(bi_l + 2 * HDIM + cb);
    br_[0] = bir4.x + bhr4.x; br_[1] = bir4.y + bhr4.y; br_[2] = bir4.z + bhr4.z; br_[3] = bir4.w + bhr4.w;
    bz_[0] = biz4.x + bhz4.x; bz_[1] = biz4.y + bhz4.y; bz_[2] = biz4.z + bhz4.z; bz_[3] = biz4.w + bhz4.w;
    bi_n[0] = bin4.x; bi_n[1] = bin4.y; bi_n[2] = bin4.z; bi_n[3] = bin4.w;
    bh_n[0] = bhn4.x; bh_n[1] = bhn4.y; bh_n[2] = bhn4.z; bh_n[3] = bhn4.w;

    // ---- publish h(0)=h0 into own ring slot T (blocked, one 8B store) ----
    float4 h4 = *(const float4*)(h0 + (size_t)l * SLOTE + (size_t)row * HDIM + cb);
    h[0] = h4.x; h[1] = h4.y; h[2] = h4.z; h[3] = h4.w;
    union { unsigned short us[4]; unsigned long long u; } pk;
#pragma unroll
    for (int r = 0; r < 4; r++) pk.us[r] = f2b(h[r]);
    unsigned short* slotT = ring_l + (size_t)T_STEPS * SLOTE;
    __hip_atomic_store((unsigned long long*)(slotT + (size_t)g * 1024 + (size_t)row * 16 + lg * 4),
                       pk.u, __ATOMIC_RELAXED, __HIP_MEMORY_SCOPE_AGENT);
  }

  // ---- x-GEMV into local accs (role: x-waves). tt = step whose gi is computed ----
  f32x4 air, aiz, ain;
  auto xgemv = [&](int tt) {
    f32x4 z = {};
    air = z; aiz = z; ain = z;
    if (l == 0) {
      const unsigned short* xa_b = xb + (size_t)tt * SLOTE + (size_t)row * KDIM + lg * 8;
#pragma unroll
      for (int kb = 0; kb < 4; kb++) {
        bf16x8 xa[8];
#pragma unroll
        for (int j = 0; j < 8; j++)
          xa[j] = *(const bf16x8*)(xa_b + (size_t)(kb * 8 + j) * 32);
#pragma unroll
        for (int j = 0; j < 8; j++) {
          int kc = kb * 8 + j;
          bf16x8 wir = *(const bf16x8*)&Wis[(size_t)kc * 512 + (size_t)lane * 8];
          bf16x8 wiz = *(const bf16x8*)&Wis[(size_t)(32 + kc) * 512 + (size_t)lane * 8];
          air = MFMA16(wir, xa[j], air);
          aiz = MFMA16(wiz, xa[j], aiz);
          ain = MFMA16(wn[kc], xa[j], ain);
        }
      }
    } else {
      const unsigned short* xa_b = prev_ring + (size_t)(T_STEPS - 1 - tt) * SLOTE
                                   + (size_t)(lg >> 1) * 1024 + (size_t)row * 16 + (lg & 1) * 8;
#pragma unroll
      for (int kb = 0; kb < 4; kb++) {
        bf16x8 xa[8];
#pragma unroll
        for (int j = 0; j < 8; j++)
          xa[j] = *(const bf16x8*)(xa_b + (size_t)(kb * 8 + j) * 2048);
#pragma unroll
        for (int j = 0; j < 8; j++) {
          int kc = kb * 8 + j;
          bf16x8 wir = *(const bf16x8*)&Wis[(size_t)kc * 512 + (size_t)lane * 8];
          bf16x8 wiz = *(const bf16x8*)&Wis[(size_t)(32 + kc) * 512 + (size_t)lane * 8];
          air = MFMA16(wir, xa[j], air);
          aiz = MFMA16(wiz, xa[j], aiz);
          ain = MFMA16(wn[kc], xa[j], ain);
        }
      }
    }
    // write gi(tt) to LDS buffer tt&1: [gate][64 rows][16 cols] f32
    float* gp = gi_lds + (size_t)(tt & 1) * 3072 + (size_t)row * 16 + lg * 4;
    *(f32x4*)(gp + 0)    = air;
    *(f32x4*)(gp + 1024) = aiz;
    *(f32x4*)(gp + 2048) = ain;
  };

  __syncthreads();   // P1: staging vmcnt drained; h0 stores at LLC
  if (tid == 0)
    __hip_atomic_store(&fl[g * FSTRIDE], 1u, __ATOMIC_RELAXED, __HIP_MEMORY_SCOPE_AGENT);

  // ---- prologue: h-waves confirm all h0 published; x-waves compute gi(0) ----
  if (is_h) {
    while (__hip_atomic_load(&fl[lane * FSTRIDE], __ATOMIC_RELAXED,
                             __HIP_MEMORY_SCOPE_AGENT) < 1u) {}
    asm volatile("" ::: "memory");
  } else {
    if (l > 0) {
      while (__hip_atomic_load(&fp[lane * FSTRIDE], __ATOMIC_RELAXED,
                               __HIP_MEMORY_SCOPE_AGENT) < 2u) {}
      asm volatile("" ::: "memory");
    }
    xgemv(0);
  }
  __syncthreads();   // P2: gi(0) visible to h-waves

#pragma unroll 1
  for (int t = 0; t < T_STEPS; t++) {
    if (is_h) {
      // ---- h(t) B-frags from own slot (T-t), blocked layout ----
      const unsigned short* ha_b = ring_l + (size_t)(T_STEPS - t) * SLOTE
                                   + (size_t)(lg >> 1) * 1024 + (size_t)row * 16 + (lg & 1) * 8;
      f32x4 ahr = {}, ahz = {}, ahn = {};
#pragma unroll
      for (int kb = 0; kb < 4; kb++) {
        bf16x8 hh[8];
#pragma unroll
        for (int j = 0; j < 8; j++)
          hh[j] = *(const bf16x8*)(ha_b + (size_t)(kb * 8 + j) * 2048);
#pragma unroll
        for (int j = 0; j < 8; j++) {
          int kc = kb * 8 + j;
          bf16x8 whr = *(const bf16x8*)&Bs[(size_t)kc * 512 + (size_t)lane * 8];
          bf16x8 whz = *(const bf16x8*)&Bs[(size_t)(32 + kc) * 512 + (size_t)lane * 8];
          ahr = MFMA16(whr, hh[j], ahr);
          ahz = MFMA16(whz, hh[j], ahz);
          ahn = MFMA16(wn[kc], hh[j], ahn);
        }
      }
      // ---- gi(t) from LDS double buffer ----
      const float* gp = gi_lds + (size_t)(t & 1) * 3072 + (size_t)row * 16 + lg * 4;
      f32x4 xir = *(const f32x4*)(gp + 0);
      f32x4 xiz = *(const f32x4*)(gp + 1024);
      f32x4 xin = *(const f32x4*)(gp + 2048);
      // ---- gates + state update ----
      unsigned short* hn = ring_l + (size_t)(T_STEPS - 1 - t) * SLOTE;  // h(t+1)
      union { unsigned short us[4]; unsigned long long u; } pk;
#pragma unroll
      for (int r = 0; r < 4; r++) {
        float xr = xir[r] + ahr[r] + br_[r];
        float xz = xiz[r] + ahz[r] + bz_[r];
        float rr = 1.0f / (1.0f + __expf(-xr));
        float zz = 1.0f / (1.0f + __expf(-xz));
        float xn = (xin[r] + bi_n[r]) + rr * (ahn[r] + bh_n[r]);
        float e2 = __expf(-2.0f * xn);
        float nn = (1.0f - e2) / (1.0f + e2);    // tanh
        float hv = (1.0f - zz) * nn + zz * h[r];
        h[r] = hv;
        pk.us[r] = f2b(hv);
      }
      __hip_atomic_store((unsigned long long*)(hn + (size_t)g * 1024 + (size_t)row * 16 + lg * 4),
                         pk.u, __ATOMIC_RELAXED, __HIP_MEMORY_SCOPE_AGENT);
      if (t == T_STEPS - 1) {
        float4 o; o.x = h[0]; o.y = h[1]; o.z = h[2]; o.w = h[3];
        *(float4*)(hout + (size_t)l * SLOTE + (size_t)row * HDIM + cb) = o;
      }
    } else if (t + 1 < T_STEPS) {
      // ---- x-waves: gi(t+1), guarded by prev-layer flag (slot T-2-t) ----
      if (l > 0) {
        while (__hip_atomic_load(&fp[lane * FSTRIDE], __ATOMIC_RELAXED,
                                 __HIP_MEMORY_SCOPE_AGENT) < (unsigned)(t + 3)) {}
        asm volatile("" ::: "memory");
      }
      xgemv(t + 1);
    }

    __syncthreads();   // B1 (uniform): h stores drained; gi(t+1) visible next iter

    if (is_h) {
      if (tid == 0)
        __hip_atomic_store(&fl[g * FSTRIDE], (unsigned)(t + 2),
                           __ATOMIC_RELAXED, __HIP_MEMORY_SCOPE_AGENT);
      if (t + 1 < T_STEPS) {
        while (__hip_atomic_load(&fl[lane * FSTRIDE], __ATOMIC_RELAXED,
                                 __HIP_MEMORY_SCOPE_AGENT) < (unsigned)(t + 2)) {}
        asm volatile("" ::: "memory");
      }
    }
  }
}

// ---------- host ----------
extern "C" void kernel_launch(void* const* d_in, const int* in_sizes, int n_in,
                              void* d_out, int out_size, void* d_ws, size_t ws_size,
                              hipStream_t stream) {
  const float* x   = (const float*)d_in[0];
  const float* h0  = (const float*)d_in[1];
  const float* wih = (const float*)d_in[2];
  const float* whh = (const float*)d_in[3];
  const float* bih = (const float*)d_in[4];
  const float* bhh = (const float*)d_in[5];
  float* out = (float*)d_out;

  char* p = (char*)d_ws;
  unsigned short* xb    = (unsigned short*)p; p += (size_t)T_STEPS * SLOTE * 2;             // 33.6 MB
  unsigned short* wswhh = (unsigned short*)p; p += (size_t)LAYERS * WSZ * 2;                // 18.9 MB
  unsigned short* wswih = (unsigned short*)p; p += (size_t)LAYERS * WSZ * 2;                // 18.9 MB
  unsigned short* rings = (unsigned short*)p; p += (size_t)LAYERS * RING_SLOTS * SLOTE * 2; // 101 MB
  unsigned int*   flags = (unsigned int*)p;   p += 4096;  // 3*64*FSTRIDE*4 = 3 KB used
  // total ~172.5 MB

  static int attr_set = 0;
  if (!attr_set) {
    hipFuncSetAttribute((const void*)gru_fused,
                        hipFuncAttributeMaxDynamicSharedMemorySize, LDS_TOTAL);
    attr_set = 1;
  }

  hipMemsetAsync(flags, 0, 4096, stream);
  f2b_kernel<<<16384, 256, 0, stream>>>(x, xb, (T_STEPS * SLOTE) / 4);
  swizzle_w<<<4608, 256, 0, stream>>>(whh, wswhh);
  swizzle_w<<<4608, 256, 0, stream>>>(wih, wswih);

  gru_fused<<<LAYERS * 64, 512, LDS_TOTAL, stream>>>(
      xb, wswhh, wswih, bih, bhh, h0, rings, out, flags);
}